// Round 3
// baseline (97.276 us; speedup 1.0000x reference)
//
#include <hip/hip_runtime.h>
#include <stdint.h>

#pragma clang fp contract(off)

// PRNG bits variant for jax_threefry_partitionable=True (default in recent JAX):
//   32-bit random_bits = bits1 ^ bits2 (XOR of the two threefry output words).
// BITS_MODE: 0 = o0^o1 (partitionable, believed correct)
//            1 = o1 only      2 = o0 only      3 = non-partitionable original
#define BITS_MODE 0

#define BB 64
#define NN 4096
#define MM 128
#define LL 21
#define DELTA_ELEMS ((size_t)BB * NN * LL * 4)   // 22020096 floats

// Per-roi scratch lives in the roi's own (not-yet-written) output block:
// slot0 = out[i*84+0] : midx (int bits)      [kernel1 -> kernel3]
// slot1 = out[i*84+1] : merged iou (float)   [kernel1 -> kernel2]
// slot2 = out[i*84+2] : sel (int bits)       [kernel2 -> kernel3]
// kernel3 reads its own slots FIRST, then overwrites the whole block.

__host__ __device__ __forceinline__ uint32_t rotl32(uint32_t v, int s) {
  return (v << s) | (v >> (32 - s));
}

// Threefry-2x32, 20 rounds (JAX's threefry2x32).
__host__ __device__ inline void threefry2x32(uint32_t k0, uint32_t k1,
                                             uint32_t x0, uint32_t x1,
                                             uint32_t* o0, uint32_t* o1) {
  const uint32_t ks2 = k0 ^ k1 ^ 0x1BD11BDAu;
  x0 += k0; x1 += k1;
#define TF_R(r) do { x0 += x1; x1 = rotl32(x1, (r)); x1 ^= x0; } while (0)
  TF_R(13); TF_R(15); TF_R(26); TF_R(6);
  x0 += k1;  x1 += ks2 + 1u;
  TF_R(17); TF_R(29); TF_R(16); TF_R(24);
  x0 += ks2; x1 += k0 + 2u;
  TF_R(13); TF_R(15); TF_R(26); TF_R(6);
  x0 += k0;  x1 += k1 + 3u;
  TF_R(17); TF_R(29); TF_R(16); TF_R(24);
  x0 += k1;  x1 += ks2 + 4u;
  TF_R(13); TF_R(15); TF_R(26); TF_R(6);
  x0 += ks2; x1 += k0 + 5u;
#undef TF_R
  *o0 = x0; *o1 = x1;
}

// random_bits(key, 32, (B,N)) element at flat index idx
__device__ __forceinline__ uint32_t jax_bits32(uint32_t ka, uint32_t kb, uint32_t idx) {
#if BITS_MODE == 0
  uint32_t o0, o1;
  threefry2x32(ka, kb, 0u, idx, &o0, &o1);   // counter (hi=0, lo=idx)
  return o0 ^ o1;                            // partitionable 32-bit fold
#elif BITS_MODE == 1
  uint32_t o0, o1;
  threefry2x32(ka, kb, 0u, idx, &o0, &o1);
  return o1;
#elif BITS_MODE == 2
  uint32_t o0, o1;
  threefry2x32(ka, kb, 0u, idx, &o0, &o1);
  return o0;
#else
  const uint32_t half = (BB * NN) / 2;
  uint32_t o0, o1;
  if (idx < half) { threefry2x32(ka, kb, idx, idx + half, &o0, &o1); return o0; }
  threefry2x32(ka, kb, idx - half, idx, &o0, &o1); return o1;
#endif
}

// jax.random.randint(key, (B,N), 1, 1280, int32) element at flat idx.
// span=1279; multiplier = (2^16 % 1279)^2 % 1279 = 882.
__device__ __forceinline__ uint32_t jax_randint_1_1280(uint32_t k1a, uint32_t k1b,
                                                       uint32_t k2a, uint32_t k2b,
                                                       uint32_t idx) {
  const uint32_t hi = jax_bits32(k1a, k1b, idx);
  const uint32_t lo = jax_bits32(k2a, k2b, idx);
  const uint32_t off = ((hi % 1279u) * 882u + (lo % 1279u)) % 1279u;
  return 1u + off;
}

// ---------------- Kernel 1: IoU max + argmax per roi ----------------
__global__ __launch_bounds__(256) void iou_kernel(const float* __restrict__ roi,
                                                  const float* __restrict__ gt,
                                                  float* __restrict__ out) {
  __shared__ float4 gtb[MM];
  const int b = blockIdx.y;
  const int t = threadIdx.x;
  if (t < MM) gtb[t] = ((const float4*)gt)[b * MM + t];
  __syncthreads();
  const int i = b * NN + blockIdx.x * 256 + t;
  const float4 r = ((const float4*)roi)[i];           // [y1,x1,y2,x2]
  const float barea = (r.z - r.x) * (r.w - r.y);
  float best = -1.0f;
  int bm = 0;
  for (int m = 0; m < MM; ++m) {
    const float4 g = gtb[m];
    const float garea = (g.z - g.x) * (g.w - g.y);
    const float xt = fmaxf(r.y, g.y);
    const float yt = fmaxf(r.x, g.x);
    const float xb = fminf(r.w, g.w);
    const float yb = fminf(r.z, g.z);
    const float iw = fmaxf(xb - xt, 0.0f);
    const float ih = fmaxf(yb - yt, 0.0f);
    const float inter = iw * ih;
    const float uni = (barea + garea) - inter;
    const float iou = inter / uni;
    if (iou > best) { best = iou; bm = m; }           // first-occurrence argmax
  }
  const size_t s = (size_t)i * (LL * 4);
  ((int*)out)[s] = bm;        // slot0: midx
  out[s + 1] = best;          // slot1: merged
}

// ---------------- Kernel 2: per-row top-128 random selection ----------------
// Equivalent to: stable argsort(-(mask*rand)); keep mask & (rank<128).
__global__ __launch_bounds__(256) void select_kernel(float* __restrict__ out,
                                                     uint32_t k1a, uint32_t k1b,
                                                     uint32_t k2a, uint32_t k2b) {
  __shared__ uint32_t hist[1280];
  __shared__ uint32_t scan[256];
  __shared__ int s_thr;
  __shared__ int s_take;
  const int b = blockIdx.x;
  const int t = threadIdx.x;
  for (int j = t; j < 1280; j += 256) hist[j] = 0u;
  if (t == 0) { s_thr = 0; s_take = 0; }
  __syncthreads();

  uint32_t rv[16];
  const int base = b * NN + t * 16;      // each thread owns 16 consecutive n
  #pragma unroll
  for (int k = 0; k < 16; ++k) {
    const int i = base + k;
    uint32_t r = 0u;
    const float merged = out[(size_t)i * (LL * 4) + 1];   // slot1
    if (merged > 0.5f) {
      r = jax_randint_1_1280(k1a, k1b, k2a, k2b, (uint32_t)i);
      atomicAdd(&hist[r], 1u);
    }
    rv[k] = r;
  }
  __syncthreads();

  // suffix sums over 5-bin chunks: scan[t] = sum of hist[j] for j >= t*5
  uint32_t chunk = 0;
  #pragma unroll
  for (int j = 0; j < 5; ++j) chunk += hist[t * 5 + j];
  scan[t] = chunk;
  __syncthreads();
  for (int off = 1; off < 256; off <<= 1) {
    const uint32_t v = (t + off < 256) ? scan[t + off] : 0u;
    __syncthreads();
    scan[t] += v;
    __syncthreads();
  }
  const uint32_t total = scan[0];
  if (total > 128u) {
    const uint32_t Sc = scan[t];
    const uint32_t Sn = (t < 255) ? scan[t + 1] : 0u;
    if (Sc >= 128u && Sn < 128u) {       // threshold bin lives in my chunk
      uint32_t s = Sn;
      #pragma unroll
      for (int j = 4; j >= 0; --j) {
        const uint32_t h = hist[t * 5 + j];
        if (s + h >= 128u) { s_thr = t * 5 + j; s_take = 128 - (int)s; break; }
        s += h;
      }
    }
  }
  __syncthreads();
  const int thr = s_thr;
  const uint32_t take = (uint32_t)s_take;

  // ordered rank among entries with rand == thr (ascending index)
  uint32_t lt = 0;
  if (thr > 0) {
    #pragma unroll
    for (int k = 0; k < 16; ++k) lt += (rv[k] == (uint32_t)thr) ? 1u : 0u;
  }
  scan[t] = lt;
  __syncthreads();
  for (int off = 1; off < 256; off <<= 1) {
    const uint32_t v = (t >= off) ? scan[t - off] : 0u;
    __syncthreads();
    scan[t] += v;
    __syncthreads();
  }
  uint32_t run = scan[t] - lt;           // exclusive prefix of ties before me

  #pragma unroll
  for (int k = 0; k < 16; ++k) {
    bool s;
    if (thr == 0) {                      // total <= 128: keep all masked
      s = rv[k] > 0u;
    } else {
      s = (rv[k] > (uint32_t)thr);
      if (rv[k] == (uint32_t)thr) { s = (run < take); ++run; }
    }
    ((int*)out)[(size_t)(base + k) * (LL * 4) + 2] = s ? 1 : 0;   // slot2
  }
}

// ---------------- Kernel 3: write full output (deltas + one-hot) ----------------
__global__ __launch_bounds__(256) void out_kernel(const float* __restrict__ roi,
                                                  const float* __restrict__ gt,
                                                  const int* __restrict__ glab,
                                                  float* __restrict__ out) {
  const int i = blockIdx.x * 256 + threadIdx.x;   // (b,n) flat
  const int b = i >> 12;
  const size_t s = (size_t)i * (LL * 4);
  const int mi  = ((const int*)out)[s];           // slot0 (read BEFORE overwrite)
  const int sv  = ((const int*)out)[s + 2];       // slot2
  float4 dv = {0.f, 0.f, 0.f, 0.f};
  int lbl = -1;
  if (sv) {
    const float4 r = ((const float4*)roi)[i];
    const float4 g = ((const float4*)gt)[b * MM + mi];
    lbl = glab[b * MM + mi];
    float bh = r.z - r.x, bw = r.w - r.y;
    const float bcy = r.x + 0.5f * bh, bcx = r.y + 0.5f * bw;
    const float gh = g.z - g.x, gw = g.w - g.y;
    const float gcy = g.x + 0.5f * gh, gcx = g.y + 0.5f * gw;
    if (bw == 0.0f) bw = 1e-3f;
    if (bh == 0.0f) bh = 1e-3f;
    const float dx = (gcx - bcx) / bw;
    const float dy = (gcy - bcy) / bh;
    const float dw = (gw == 0.0f) ? 0.0f : logf(gw / bw);
    const float dh = (gh == 0.0f) ? 0.0f : logf(gh / bh);
    dv.x = dy / 0.1f; dv.y = dx / 0.1f; dv.z = dh / 0.2f; dv.w = dw / 0.2f;
  }
  const float4 z = {0.f, 0.f, 0.f, 0.f};
  float4* dst = (float4*)out + (size_t)i * LL;
  #pragma unroll
  for (int l = 0; l < LL; ++l) dst[l] = (l == lbl) ? dv : z;
  float* lp = out + DELTA_ELEMS + (size_t)i * LL;
  #pragma unroll
  for (int l = 0; l < LL; ++l) lp[l] = (l == lbl) ? 1.0f : 0.0f;
}

extern "C" void kernel_launch(void* const* d_in, const int* in_sizes, int n_in,
                              void* d_out, int out_size, void* d_ws, size_t ws_size,
                              hipStream_t stream) {
  const float* roi = (const float*)d_in[0];
  const float* gt  = (const float*)d_in[1];
  const int* glab  = (const int*)d_in[2];
  float* out = (float*)d_out;

  // Host-side JAX key derivation:
  // key(42) = (0,42); kp,kn = split(key); inside randint: hk,lk = split(kp)
  // Foldlike split (partitionable): key_i = BOTH words of threefry(key,(0,i)).
  uint32_t kp0, kp1, k1a, k1b, k2a, k2b;
#if BITS_MODE <= 2
  threefry2x32(0u, 42u, 0u, 0u, &kp0, &kp1);     // kp = split[0]
  threefry2x32(kp0, kp1, 0u, 0u, &k1a, &k1b);    // higher-bits key
  threefry2x32(kp0, kp1, 0u, 1u, &k2a, &k2b);    // lower-bits key
#else
  uint32_t w00, w10, w01, w11;
  threefry2x32(0u, 42u, 0u, 2u, &w00, &w10);
  threefry2x32(0u, 42u, 1u, 3u, &w01, &w11);
  kp0 = w00; kp1 = w01;                          // kp = (out0[0], out0[1])
  threefry2x32(kp0, kp1, 0u, 2u, &w00, &w10);
  threefry2x32(kp0, kp1, 1u, 3u, &w01, &w11);
  k1a = w00; k1b = w01; k2a = w10; k2b = w11;
#endif

  hipLaunchKernelGGL(iou_kernel, dim3(NN / 256, BB), dim3(256), 0, stream,
                     roi, gt, out);
  hipLaunchKernelGGL(select_kernel, dim3(BB), dim3(256), 0, stream,
                     out, k1a, k1b, k2a, k2b);
  hipLaunchKernelGGL(out_kernel, dim3(BB * NN / 256), dim3(256), 0, stream,
                     roi, gt, glab, out);
}

// Round 4
// 64.450 us; speedup vs baseline: 1.5093x; 1.5093x over previous
//
#include <hip/hip_runtime.h>
#include <stdint.h>

#pragma clang fp contract(off)

// PRNG: jax_threefry_partitionable 32-bit random_bits = o0 ^ o1 (VERIFIED round 3)

#define BB 64
#define NN 4096
#define MM 128
#define LL 21
#define NTOT (BB * NN)                           // 262144 rois
#define DELTA_ELEMS ((size_t)BB * NN * LL * 4)   // 22020096 floats

__host__ __device__ __forceinline__ uint32_t rotl32(uint32_t v, int s) {
  return (v << s) | (v >> (32 - s));
}

// Threefry-2x32, 20 rounds (JAX's threefry2x32).
__host__ __device__ inline void threefry2x32(uint32_t k0, uint32_t k1,
                                             uint32_t x0, uint32_t x1,
                                             uint32_t* o0, uint32_t* o1) {
  const uint32_t ks2 = k0 ^ k1 ^ 0x1BD11BDAu;
  x0 += k0; x1 += k1;
#define TF_R(r) do { x0 += x1; x1 = rotl32(x1, (r)); x1 ^= x0; } while (0)
  TF_R(13); TF_R(15); TF_R(26); TF_R(6);
  x0 += k1;  x1 += ks2 + 1u;
  TF_R(17); TF_R(29); TF_R(16); TF_R(24);
  x0 += ks2; x1 += k0 + 2u;
  TF_R(13); TF_R(15); TF_R(26); TF_R(6);
  x0 += k0;  x1 += k1 + 3u;
  TF_R(17); TF_R(29); TF_R(16); TF_R(24);
  x0 += k1;  x1 += ks2 + 4u;
  TF_R(13); TF_R(15); TF_R(26); TF_R(6);
  x0 += ks2; x1 += k0 + 5u;
#undef TF_R
  *o0 = x0; *o1 = x1;
}

__device__ __forceinline__ uint32_t jax_bits32(uint32_t ka, uint32_t kb, uint32_t idx) {
  uint32_t o0, o1;
  threefry2x32(ka, kb, 0u, idx, &o0, &o1);   // counter (hi=0, lo=idx)
  return o0 ^ o1;                            // partitionable 32-bit fold
}

// jax.random.randint(key, (B,N), 1, 1280): span=1279, mult=(2^16%1279)^2%1279=882
__device__ __forceinline__ uint32_t jax_randint_1_1280(uint32_t k1a, uint32_t k1b,
                                                       uint32_t k2a, uint32_t k2b,
                                                       uint32_t idx) {
  const uint32_t hi = jax_bits32(k1a, k1b, idx);
  const uint32_t lo = jax_bits32(k2a, k2b, idx);
  const uint32_t off = ((hi % 1279u) * 882u + (lo % 1279u)) % 1279u;
  return 1u + off;
}

// ---------------- Kernel 1: IoU max + argmax per roi ----------------
// midx/merged are indexed as [i*stride] (stride=1: compact ws; stride=84: out-slots)
__global__ __launch_bounds__(256) void iou_kernel(const float* __restrict__ roi,
                                                  const float* __restrict__ gt,
                                                  int* __restrict__ midx,
                                                  float* __restrict__ merged,
                                                  int stride) {
  __shared__ float4 gtb[MM];
  __shared__ float gar[MM];
  const int b = blockIdx.y;
  const int t = threadIdx.x;
  if (t < MM) {
    const float4 g = ((const float4*)gt)[b * MM + t];
    gtb[t] = g;
    gar[t] = (g.z - g.x) * (g.w - g.y);
  }
  __syncthreads();
  const int i = b * NN + blockIdx.x * 256 + t;
  const float4 r = ((const float4*)roi)[i];           // [y1,x1,y2,x2]
  const float barea = (r.z - r.x) * (r.w - r.y);
  float best = -1.0f;
  int bm = 0;
  for (int m = 0; m < MM; ++m) {
    const float4 g = gtb[m];
    const float xt = fmaxf(r.y, g.y);
    const float yt = fmaxf(r.x, g.x);
    const float xb = fminf(r.w, g.w);
    const float yb = fminf(r.z, g.z);
    const float iw = fmaxf(xb - xt, 0.0f);
    const float ih = fmaxf(yb - yt, 0.0f);
    const float inter = iw * ih;
    const float uni = (barea + gar[m]) - inter;
    const float iou = inter / uni;                    // IEEE div, bit-exact vs ref
    if (iou > best) { best = iou; bm = m; }           // first-occurrence argmax
  }
  midx[(size_t)i * stride] = bm;
  merged[(size_t)i * stride] = best;
}

// ---------------- Kernel 2: per-row top-128 random selection ----------------
// Equivalent to: stable argsort(-(mask*rand)); keep mask & (rank<128).
__global__ __launch_bounds__(256) void select_kernel(const float* __restrict__ merged,
                                                     int* __restrict__ sel,
                                                     int stride,
                                                     uint32_t k1a, uint32_t k1b,
                                                     uint32_t k2a, uint32_t k2b) {
  __shared__ uint32_t buf[NN];        // staged merged bits, later staged sel
  __shared__ uint32_t hist[1280];
  __shared__ uint32_t scan[256];
  __shared__ int s_thr;
  __shared__ int s_take;
  const int b = blockIdx.x;
  const int t = threadIdx.x;
  for (int j = t; j < 1280; j += 256) hist[j] = 0u;
  if (t == 0) { s_thr = 0; s_take = 0; }
  // coalesced stage of the row's merged values
  #pragma unroll
  for (int k = 0; k < 16; ++k) {
    const int li = t + k * 256;
    buf[li] = __float_as_uint(merged[(size_t)(b * NN + li) * stride]);
  }
  __syncthreads();

  uint32_t rv[16];
  const int lbase = t * 16;           // thread owns 16 consecutive n (tie order!)
  #pragma unroll
  for (int k = 0; k < 16; ++k) {
    const int li = lbase + k;
    uint32_t r = 0u;
    if (__uint_as_float(buf[li]) > 0.5f) {
      r = jax_randint_1_1280(k1a, k1b, k2a, k2b, (uint32_t)(b * NN + li));
      atomicAdd(&hist[r], 1u);
    }
    rv[k] = r;
  }
  __syncthreads();

  // suffix sums over 5-bin chunks: scan[t] = sum of hist[j] for j >= t*5
  uint32_t chunk = 0;
  #pragma unroll
  for (int j = 0; j < 5; ++j) chunk += hist[t * 5 + j];
  scan[t] = chunk;
  __syncthreads();
  for (int off = 1; off < 256; off <<= 1) {
    const uint32_t v = (t + off < 256) ? scan[t + off] : 0u;
    __syncthreads();
    scan[t] += v;
    __syncthreads();
  }
  const uint32_t total = scan[0];
  if (total > 128u) {
    const uint32_t Sc = scan[t];
    const uint32_t Sn = (t < 255) ? scan[t + 1] : 0u;
    if (Sc >= 128u && Sn < 128u) {       // threshold bin lives in my chunk
      uint32_t s = Sn;
      #pragma unroll
      for (int j = 4; j >= 0; --j) {
        const uint32_t h = hist[t * 5 + j];
        if (s + h >= 128u) { s_thr = t * 5 + j; s_take = 128 - (int)s; break; }
        s += h;
      }
    }
  }
  __syncthreads();
  const int thr = s_thr;
  const uint32_t take = (uint32_t)s_take;

  // ordered rank among entries with rand == thr (ascending index)
  uint32_t lt = 0;
  if (thr > 0) {
    #pragma unroll
    for (int k = 0; k < 16; ++k) lt += (rv[k] == (uint32_t)thr) ? 1u : 0u;
  }
  scan[t] = lt;
  __syncthreads();
  for (int off = 1; off < 256; off <<= 1) {
    const uint32_t v = (t >= off) ? scan[t - off] : 0u;
    __syncthreads();
    scan[t] += v;
    __syncthreads();
  }
  uint32_t run = scan[t] - lt;           // exclusive prefix of ties before me

  #pragma unroll
  for (int k = 0; k < 16; ++k) {
    bool s;
    if (thr == 0) {                      // total <= 128: keep all masked
      s = rv[k] > 0u;
    } else {
      s = (rv[k] > (uint32_t)thr);
      if (rv[k] == (uint32_t)thr) { s = (run < take); ++run; }
    }
    buf[lbase + k] = s ? 1u : 0u;        // stage sel in LDS
  }
  __syncthreads();
  // coalesced sel store
  #pragma unroll
  for (int k = 0; k < 16; ++k) {
    const int li = t + k * 256;
    sel[(size_t)(b * NN + li) * stride] = (int)buf[li];
  }
}

// ---------------- Kernel 3: cooperative coalesced output write ----------------
// Block owns 256 rois: reads per-roi state, computes (dv,lbl) into LDS, then the
// whole block writes its contiguous delta region (5376 float4) and label region
// (1344 float4) with lane-consecutive stores.
__global__ __launch_bounds__(256) void out_kernel(const float* __restrict__ roi,
                                                  const float* __restrict__ gt,
                                                  const int* __restrict__ glab,
                                                  const int* __restrict__ midx,
                                                  const int* __restrict__ sel,
                                                  int stride,
                                                  float* __restrict__ out) {
  __shared__ float4 sdv[256];
  __shared__ int slbl[256];
  const int t = threadIdx.x;
  const int ri0 = blockIdx.x * 256;
  const int i = ri0 + t;
  const int b = i >> 12;
  // read BEFORE this block overwrites its region (slots mode aliases out)
  const int mi = midx[(size_t)i * stride];
  const int sv = sel[(size_t)i * stride];
  float4 dv = {0.f, 0.f, 0.f, 0.f};
  int lbl = -1;
  if (sv) {
    const float4 r = ((const float4*)roi)[i];
    const float4 g = ((const float4*)gt)[b * MM + mi];
    lbl = glab[b * MM + mi];
    float bh = r.z - r.x, bw = r.w - r.y;
    const float bcy = r.x + 0.5f * bh, bcx = r.y + 0.5f * bw;
    const float gh = g.z - g.x, gw = g.w - g.y;
    const float gcy = g.x + 0.5f * gh, gcx = g.y + 0.5f * gw;
    if (bw == 0.0f) bw = 1e-3f;
    if (bh == 0.0f) bh = 1e-3f;
    const float dx = (gcx - bcx) / bw;
    const float dy = (gcy - bcy) / bh;
    const float dw = (gw == 0.0f) ? 0.0f : logf(gw / bw);
    const float dh = (gh == 0.0f) ? 0.0f : logf(gh / bh);
    dv.x = dy / 0.1f; dv.y = dx / 0.1f; dv.z = dh / 0.2f; dv.w = dw / 0.2f;
  }
  sdv[t] = dv;
  slbl[t] = lbl;
  __syncthreads();

  const float4 z = {0.f, 0.f, 0.f, 0.f};
  // Phase 1: deltas — block region = [ri0*84, ri0*84+21504) floats = 5376 float4
  float4* dbase = (float4*)out + (size_t)ri0 * LL;   // ri0*21 float4s
  #pragma unroll
  for (int k = 0; k < LL; ++k) {
    const int q = t + k * 256;          // 0..5375
    const int r = q / 21;               // magic-mul
    const int f = q - r * 21;
    dbase[q] = (f == slbl[r]) ? sdv[r] : z;
  }
  // Phase 2: labels — block region = 5376 floats = 1344 float4
  float4* lbase = (float4*)(out + DELTA_ELEMS) + (size_t)ri0 * LL / 4;
  for (int q = t; q < 1344; q += 256) {
    const int e0 = q * 4;
    float4 v;
    {
      const int r0 = e0 / 21;       v.x = ((e0 - r0 * 21) == slbl[r0]) ? 1.f : 0.f;
      const int r1 = (e0 + 1) / 21; v.y = ((e0 + 1 - r1 * 21) == slbl[r1]) ? 1.f : 0.f;
      const int r2 = (e0 + 2) / 21; v.z = ((e0 + 2 - r2 * 21) == slbl[r2]) ? 1.f : 0.f;
      const int r3 = (e0 + 3) / 21; v.w = ((e0 + 3 - r3 * 21) == slbl[r3]) ? 1.f : 0.f;
    }
    lbase[q] = v;
  }
}

extern "C" void kernel_launch(void* const* d_in, const int* in_sizes, int n_in,
                              void* d_out, int out_size, void* d_ws, size_t ws_size,
                              hipStream_t stream) {
  const float* roi = (const float*)d_in[0];
  const float* gt  = (const float*)d_in[1];
  const int* glab  = (const int*)d_in[2];
  float* out = (float*)d_out;

  // Host-side JAX key derivation (foldlike split):
  // key(42)=(0,42); kp=threefry(key,(0,0)); hi_key=threefry(kp,(0,0)); lo_key=threefry(kp,(0,1))
  uint32_t kp0, kp1, k1a, k1b, k2a, k2b;
  threefry2x32(0u, 42u, 0u, 0u, &kp0, &kp1);
  threefry2x32(kp0, kp1, 0u, 0u, &k1a, &k1b);
  threefry2x32(kp0, kp1, 0u, 1u, &k2a, &k2b);

  // Scratch: prefer compact coalesced arrays in d_ws; fall back to slots
  // embedded in the (not-yet-written) output blocks if ws is too small.
  int* midx;
  float* merged;
  int* sel;
  int stride;
  if (d_ws != nullptr && ws_size >= (size_t)3 * NTOT * 4) {
    char* ws = (char*)d_ws;
    midx   = (int*)ws;
    merged = (float*)(ws + (size_t)NTOT * 4);
    sel    = (int*)(ws + (size_t)2 * NTOT * 4);
    stride = 1;
  } else {
    midx   = (int*)out;          // slot0 of each 84-float block
    merged = out + 1;            // slot1
    sel    = (int*)out + 2;      // slot2
    stride = LL * 4;             // 84
  }

  hipLaunchKernelGGL(iou_kernel, dim3(NN / 256, BB), dim3(256), 0, stream,
                     roi, gt, midx, merged, stride);
  hipLaunchKernelGGL(select_kernel, dim3(BB), dim3(256), 0, stream,
                     merged, sel, stride, k1a, k1b, k2a, k2b);
  hipLaunchKernelGGL(out_kernel, dim3(NTOT / 256), dim3(256), 0, stream,
                     roi, gt, glab, midx, sel, stride, out);
}